// Round 7
// baseline (124.532 us; speedup 1.0000x reference)
//
#include <hip/hip_runtime.h>
#include <hip/hip_bf16.h>

typedef __bf16 bf16x8 __attribute__((ext_vector_type(8)));
typedef float  f32x4  __attribute__((ext_vector_type(4)));

#define NTILES 16384               // 262144 rows / 16

// ---------------------------------------------------------------------------
// Kernel 1 (one-shot, 64 blocks): expand quaternion weight (32,32,4) ->
// W_eff (128x128) in bf16, MFMA A-fragment order, k-axis permuted so the main
// kernel's x loads are full-granule coalesced (verified rounds 1-6):
//   element j of fragment (nt,kb,lane) holds physical
//     k = kb*32 + (j<4 ? g*4+j : 16 + g*4 + (j-4)),  g = lane>>4
// ---------------------------------------------------------------------------
__global__ __launch_bounds__(256) void prep_wfrag(const float* __restrict__ w,
                                                  ushort* __restrict__ wfrag) {
    int t = blockIdx.x * 256 + threadIdx.x;
    if (t >= 128 * 128) return;
    int j    = t & 7;
    int lane = (t >> 3) & 63;
    int kb   = (t >> 9) & 3;
    int nt   = t >> 11;
    int g    = lane >> 4;
    int n = nt * 16 + (lane & 15);
    int k = kb * 32 + (j < 4 ? g * 4 + j : 16 + g * 4 + (j - 4));
    int o  = n >> 2, c = n & 3;
    int nq = k >> 2, d = k & 3;
    int comp = c ^ d;
    bool neg = (d != 0) && ((c == 0) || (c != d && d != (c % 3) + 1));
    float val = w[o * 128 + nq * 4 + comp];
    val = neg ? -val : val;
    __bf16 bv = (__bf16)val;
    wfrag[t] = *reinterpret_cast<ushort*>(&bv);
}

// ---------------------------------------------------------------------------
// Kernel 2: out = x @ W_eff^T + bias.  2 ADJACENT tiles per wave (linear
// address walk -> L3-friendly).  All 16 x-loads are pinned BEFORE compute by
// sched_group_barrier(VMEM_READ,16) -> compiler emits counted vmcnt(8) for
// tile-0's cvt while tile-1's loads stay in flight under tile-0's compute.
// ---------------------------------------------------------------------------
__global__ __launch_bounds__(256, 4) void qgemm(const float* __restrict__ x,
                                                const ushort* __restrict__ wfrag,
                                                const float* __restrict__ bias,
                                                float* __restrict__ out) {
    __shared__ __align__(16) ushort wlds[16384];   // 32 KB fragment-ordered W
    __shared__ __align__(16) float  sbias[128];

    int tid = threadIdx.x;
    {   // setup: linear 32 KB copy (L2-hot after first blocks)
        const int4* src = (const int4*)wfrag;
        int4*       dst = (int4*)wlds;
#pragma unroll
        for (int i = 0; i < 8; ++i) dst[tid + i * 256] = src[tid + i * 256];
    }
    if (tid < 128) sbias[tid] = bias[tid];

    int lane  = tid & 63;
    int wid   = tid >> 6;      // 0..3
    int row16 = lane & 15;     // batch row within tile == D col
    int kgrp  = lane >> 4;     // 0..3
    int loff  = row16 * 128 + kgrp * 4;   // per-lane float offset within a tile

    __syncthreads();

    const bf16x8* blds = (const bf16x8*)wlds;
    size_t t0 = ((size_t)blockIdx.x * 4 + wid) * 2;   // tiles t0, t0+1 (adjacent)

    // ---- issue ALL 16 global loads (both tiles) ----
    const float4* xv = (const float4*)(x + t0 * 2048 + loff);
    float4 rA[8], rB[8];
#pragma unroll
    for (int kb = 0; kb < 4; ++kb) {
        rA[2 * kb]     = xv[kb * 8];
        rA[2 * kb + 1] = xv[kb * 8 + 4];
    }
#pragma unroll
    for (int kb = 0; kb < 4; ++kb) {
        rB[2 * kb]     = xv[512 + kb * 8];        // +2048 floats = next tile
        rB[2 * kb + 1] = xv[512 + kb * 8 + 4];
    }
    // Pin: exactly 16 VMEM reads before anything else in this region.
    __builtin_amdgcn_sched_group_barrier(0x20 /*VMEM_READ*/, 16, 0);

    auto compute_tile = [&](const float4* r, size_t tile) {
        bf16x8 afr[4];
#pragma unroll
        for (int kb = 0; kb < 4; ++kb) {
            float4 p = r[2 * kb], q = r[2 * kb + 1];
            afr[kb][0] = (__bf16)p.x; afr[kb][1] = (__bf16)p.y;
            afr[kb][2] = (__bf16)p.z; afr[kb][3] = (__bf16)p.w;
            afr[kb][4] = (__bf16)q.x; afr[kb][5] = (__bf16)q.y;
            afr[kb][6] = (__bf16)q.z; afr[kb][7] = (__bf16)q.w;
        }
        // D layout: col = lane&15 = batch row, row = kgrp*4 + reg = feature.
        float* op = out + tile * 2048 + loff;
#pragma unroll
        for (int nt = 0; nt < 8; ++nt) {
            f32x4 acc = *(const f32x4*)&sbias[nt * 16 + kgrp * 4];
#pragma unroll
            for (int kb = 0; kb < 4; ++kb) {
                bf16x8 wfr = blds[(nt * 4 + kb) * 64 + lane];
                acc = __builtin_amdgcn_mfma_f32_16x16x32_bf16(wfr, afr[kb], acc, 0, 0, 0);
            }
            *(f32x4*)(op + nt * 16) = acc;
        }
    };

    compute_tile(rA, t0);       // waits vmcnt(8): tile-1 loads stay in flight
    compute_tile(rB, t0 + 1);
}

extern "C" void kernel_launch(void* const* d_in, const int* in_sizes, int n_in,
                              void* d_out, int out_size, void* d_ws, size_t ws_size,
                              hipStream_t stream) {
    const float* x      = (const float*)d_in[0];   // [262144,128] fp32
    const float* weight = (const float*)d_in[1];   // [32,32,4] fp32
    const float* bias   = (const float*)d_in[2];   // [128] fp32
    float*       out    = (float*)d_out;           // [262144,128] fp32
    ushort*      wfrag  = (ushort*)d_ws;           // 32 KB fragment-ordered W_eff

    prep_wfrag<<<64, 256, 0, stream>>>(weight, wfrag);
    qgemm<<<2048, 256, 0, stream>>>(x, wfrag, bias, out);
}

// Round 8
// 63.261 us; speedup vs baseline: 1.9685x; 1.9685x over previous
//
#include <hip/hip_runtime.h>
#include <hip/hip_bf16.h>

typedef __bf16 bf16x8 __attribute__((ext_vector_type(8)));
typedef float  f32x4  __attribute__((ext_vector_type(4)));

#define NTILES 16384               // 262144 rows / 16

// ---------------------------------------------------------------------------
// Kernel 1 (one-shot): expand quaternion weight (32,32,4) -> W_eff (128x128)
// bf16, MFMA A-fragment order, NATURAL k order (no permutation this round):
//   element j of fragment (nt,kb,lane) = W_eff[nt*16+(lane&15)][kb*32+(lane>>4)*8+j]
// ---------------------------------------------------------------------------
__global__ __launch_bounds__(256) void prep_wfrag(const float* __restrict__ w,
                                                  ushort* __restrict__ wfrag) {
    int t = blockIdx.x * 256 + threadIdx.x;
    if (t >= 128 * 128) return;
    int j    = t & 7;
    int lane = (t >> 3) & 63;
    int kb   = (t >> 9) & 3;
    int nt   = t >> 11;
    int g    = lane >> 4;
    int n = nt * 16 + (lane & 15);      // output feature
    int k = kb * 32 + g * 8 + j;        // input feature (natural order)
    int o  = n >> 2, c = n & 3;
    int nq = k >> 2, d = k & 3;
    int comp = c ^ d;                   // Hamilton tables (verified r1-r7)
    bool neg = (d != 0) && ((c == 0) || (c != d && d != (c % 3) + 1));
    float val = w[o * 128 + nq * 4 + comp];
    val = neg ? -val : val;
    __bf16 bv = (__bf16)val;
    wfrag[t] = *reinterpret_cast<ushort*>(&bv);
}

// ---------------------------------------------------------------------------
// Kernel 2: out = x @ W_eff^T + bias.  ALL global traffic is contiguous
// 1KB-per-instruction (copy-bench shape); fragment scatter/gather happens in
// a wave-private 8KB LDS buffer with XOR swizzle  addr(row,chunk) =
// row*512B + ((chunk ^ (row&7))*16B)  -- uniform bank use in all 4 phases.
// 2 adjacent tiles per wave, both tiles' loads issued up front.
// ---------------------------------------------------------------------------
__global__ __launch_bounds__(256) void qgemm(const float* __restrict__ x,
                                             const ushort* __restrict__ wfrag,
                                             const float* __restrict__ bias,
                                             float* __restrict__ out) {
    __shared__ __align__(16) ushort wlds[16384];      // 32 KB W fragments
    __shared__ __align__(16) float  xstage[4][2048];  // 8 KB per wave

    int tid   = threadIdx.x;
    int lane  = tid & 63;
    int wid   = tid >> 6;      // 0..3
    int row16 = lane & 15;
    int kgrp  = lane >> 4;     // 0..3
    float* xw = xstage[wid];

    size_t t0 = ((size_t)blockIdx.x * 4 + wid) * 2;   // tiles t0, t0+1 (adjacent)

    // ---- contiguous global loads: 1KB per instruction, both tiles ----
    const f32x4* xs0 = (const f32x4*)(x + t0 * 2048);
    const f32x4* xs1 = (const f32x4*)(x + (t0 + 1) * 2048);
    f32x4 rA[8], rB[8];
#pragma unroll
    for (int s = 0; s < 8; ++s) rA[s] = xs0[lane + 64 * s];
#pragma unroll
    for (int s = 0; s < 8; ++s) rB[s] = xs1[lane + 64 * s];

    // ---- W -> LDS (32 KB linear copy), bias -> registers ----
    {
        const int4* src = (const int4*)wfrag;
        int4*       dst = (int4*)wlds;
#pragma unroll
        for (int i = 0; i < 8; ++i) dst[tid + i * 256] = src[tid + i * 256];
    }
    f32x4 bv[8];
#pragma unroll
    for (int nt = 0; nt < 8; ++nt) bv[nt] = *(const f32x4*)(bias + nt * 16 + kgrp * 4);
    __syncthreads();   // only barrier in the kernel

    const bf16x8* blds = (const bf16x8*)wlds;

#pragma unroll
    for (int tt = 0; tt < 2; ++tt) {
        const f32x4* r   = tt ? rB : rA;
        size_t tile      = t0 + tt;

        // 1) stage x -> LDS (swizzled; conflict-uniform)
#pragma unroll
        for (int s = 0; s < 8; ++s) {
            int row = 2 * s + (lane >> 5);
            int c   = lane & 31;
            *(f32x4*)(xw + row * 128 + ((c ^ (row & 7)) << 2)) = r[s];
        }

        // 2) fragment reads + cvt (all afr in regs before stage reuse)
        bf16x8 afr[4];
#pragma unroll
        for (int kb = 0; kb < 4; ++kb) {
            int c0 = kb * 8 + kgrp * 2;
            f32x4 lo = *(const f32x4*)(xw + row16 * 128 + ((c0 ^ (row16 & 7)) << 2));
            f32x4 hi = *(const f32x4*)(xw + row16 * 128 + (((c0 + 1) ^ (row16 & 7)) << 2));
            afr[kb][0] = (__bf16)lo[0]; afr[kb][1] = (__bf16)lo[1];
            afr[kb][2] = (__bf16)lo[2]; afr[kb][3] = (__bf16)lo[3];
            afr[kb][4] = (__bf16)hi[0]; afr[kb][5] = (__bf16)hi[1];
            afr[kb][6] = (__bf16)hi[2]; afr[kb][7] = (__bf16)hi[3];
        }

        // 3) MFMA; acc -> LDS in swizzled layout (reuses xw after frag reads;
        //    same-wave DS ordering makes this safe, no barrier needed)
#pragma unroll
        for (int nt = 0; nt < 8; ++nt) {
            f32x4 acc = bv[nt];
#pragma unroll
            for (int kb = 0; kb < 4; ++kb) {
                bf16x8 wfr = blds[(nt * 4 + kb) * 64 + lane];
                acc = __builtin_amdgcn_mfma_f32_16x16x32_bf16(wfr, afr[kb], acc, 0, 0, 0);
            }
            int c = nt * 4 + kgrp;   // feature chunk; (nt,kgrp)<->c bijective
            *(f32x4*)(xw + row16 * 128 + ((c ^ (row16 & 7)) << 2)) = acc;
        }

        // 4) contiguous stores: 1KB per instruction
        f32x4* os = (f32x4*)(out + tile * 2048);
#pragma unroll
        for (int s = 0; s < 8; ++s) {
            int row = 2 * s + (lane >> 5);
            int c   = lane & 31;
            f32x4 v = *(const f32x4*)(xw + row * 128 + ((c ^ (row & 7)) << 2));
            os[lane + 64 * s] = v;
        }
    }
}

extern "C" void kernel_launch(void* const* d_in, const int* in_sizes, int n_in,
                              void* d_out, int out_size, void* d_ws, size_t ws_size,
                              hipStream_t stream) {
    const float* x      = (const float*)d_in[0];   // [262144,128] fp32
    const float* weight = (const float*)d_in[1];   // [32,32,4] fp32
    const float* bias   = (const float*)d_in[2];   // [128] fp32
    float*       out    = (float*)d_out;           // [262144,128] fp32
    ushort*      wfrag  = (ushort*)d_ws;           // 32 KB fragment-ordered W_eff

    prep_wfrag<<<64, 256, 0, stream>>>(weight, wfrag);
    qgemm<<<2048, 256, 0, stream>>>(x, wfrag, bias, out);
}

// Round 10
// 49.222 us; speedup vs baseline: 2.5300x; 1.2852x over previous
//
#include <hip/hip_runtime.h>
#include <hip/hip_bf16.h>

typedef __bf16 bf16x8 __attribute__((ext_vector_type(8)));
typedef float  f32x4  __attribute__((ext_vector_type(4)));

#define NTILES 16384               // 262144 rows / 16

// ---------------------------------------------------------------------------
// Kernel 1 (one-shot): expand quaternion weight (32,32,4) -> W_eff (128x128)
// bf16, MFMA A-fragment order, k-axis PERMUTED for full-granule direct loads
// (verbatim r4/r5, HW-verified):
//   element j of fragment (nt,kb,lane) holds physical
//     k = kb*32 + (j<4 ? g*4+j : 16 + g*4 + (j-4)),  g = lane>>4
// ---------------------------------------------------------------------------
__global__ __launch_bounds__(256) void prep_wfrag(const float* __restrict__ w,
                                                  ushort* __restrict__ wfrag) {
    int t = blockIdx.x * 256 + threadIdx.x;
    if (t >= 128 * 128) return;
    int j    = t & 7;
    int lane = (t >> 3) & 63;
    int kb   = (t >> 9) & 3;
    int nt   = t >> 11;
    int g    = lane >> 4;
    int n = nt * 16 + (lane & 15);
    int k = kb * 32 + (j < 4 ? g * 4 + j : 16 + g * 4 + (j - 4));
    int o  = n >> 2, c = n & 3;
    int nq = k >> 2, d = k & 3;
    int comp = c ^ d;                   // Hamilton tables (verified r1-r8)
    bool neg = (d != 0) && ((c == 0) || (c != d && d != (c % 3) + 1));
    float val = w[o * 128 + nq * 4 + comp];
    val = neg ? -val : val;
    __bf16 bv = (__bf16)val;
    wfrag[t] = *reinterpret_cast<ushort*>(&bv);
}

// ---------------------------------------------------------------------------
// Kernel 2: out = x @ W_eff^T + bias.  Flat r5 structure (1 tile/wave).
//  - input: k-permuted direct register loads (r4/r5 path, granule-clean)
//  - output: after a block barrier, wlds (W dead by then) is reused as
//    4 x 8KB per-wave staging; full-wave swizzled acc writes, explicit
//    lgkmcnt(0), then 8 x 1KB-contiguous NON-TEMPORAL stores (full lines).
// ---------------------------------------------------------------------------
__global__ __launch_bounds__(256, 4) void qgemm(const float* __restrict__ x,
                                                const ushort* __restrict__ wfrag,
                                                const float* __restrict__ bias,
                                                float* __restrict__ out) {
    __shared__ __align__(16) ushort wlds[16384];   // 32 KB: W fragments, later store stage
    __shared__ __align__(16) float  sbias[128];

    int tid   = threadIdx.x;
    int lane  = tid & 63;
    int wid   = tid >> 6;      // 0..3
    int row16 = lane & 15;
    int kgrp  = lane >> 4;     // 0..3
    int loff  = row16 * 128 + kgrp * 4;

    // 1) W-copy loads first (x loads stay in flight through the ds_write wait)
    int4 wtmp[8];
    {
        const int4* src = (const int4*)wfrag;
#pragma unroll
        for (int i = 0; i < 8; ++i) wtmp[i] = src[tid + i * 256];
    }

    // 2) x loads (8 x dwordx4, full-granule coalesced via k-permutation)
    size_t tile = (size_t)blockIdx.x * 4 + wid;    // 0..16383
    const float4* xv = (const float4*)(x + tile * 2048 + loff);
    float4 r[8];
#pragma unroll
    for (int kb = 0; kb < 4; ++kb) {
        r[2 * kb]     = xv[kb * 8];
        r[2 * kb + 1] = xv[kb * 8 + 4];
    }

    // 3) W -> LDS, bias -> LDS, barrier
    {
        int4* dst = (int4*)wlds;
#pragma unroll
        for (int i = 0; i < 8; ++i) dst[tid + i * 256] = wtmp[i];
    }
    if (tid < 128) sbias[tid] = bias[tid];
    __syncthreads();

    // 4) cvt x -> bf16 fragments
    bf16x8 afr[4];
#pragma unroll
    for (int kb = 0; kb < 4; ++kb) {
        float4 p = r[2 * kb], q = r[2 * kb + 1];
        afr[kb][0] = (__bf16)p.x; afr[kb][1] = (__bf16)p.y;
        afr[kb][2] = (__bf16)p.z; afr[kb][3] = (__bf16)p.w;
        afr[kb][4] = (__bf16)q.x; afr[kb][5] = (__bf16)q.y;
        afr[kb][6] = (__bf16)q.z; afr[kb][7] = (__bf16)q.w;
    }

    // 5) MFMA: acc[nt] = features nt*16+kgrp*4..+3 of batch row row16 (+bias)
    const bf16x8* blds = (const bf16x8*)wlds;
    f32x4 acc[8];
#pragma unroll
    for (int nt = 0; nt < 8; ++nt) {
        acc[nt] = *(const f32x4*)&sbias[nt * 16 + kgrp * 4];
#pragma unroll
        for (int kb = 0; kb < 4; ++kb) {
            bf16x8 wfr = blds[(nt * 4 + kb) * 64 + lane];
            acc[nt] = __builtin_amdgcn_mfma_f32_16x16x32_bf16(wfr, afr[kb], acc[nt], 0, 0, 0);
        }
    }

    // 6) all waves done reading W -> wlds reusable as store stage
    __syncthreads();

    // 7) stage acc into my wave's 8KB slice, XOR-swizzled:
    //    logical chunk c (= nt*4+kgrp, features 4c..4c+3) of row row16 lives at
    //    physical chunk c ^ (row16&7).  Full-wave, no divergence.
    float* stg = (float*)wlds + wid * 2048;
#pragma unroll
    for (int nt = 0; nt < 8; ++nt) {
        int c = nt * 4 + kgrp;
        *(f32x4*)(stg + row16 * 128 + ((c ^ (row16 & 7)) << 2)) = acc[nt];
    }
    asm volatile("s_waitcnt lgkmcnt(0)" ::: "memory");
    __builtin_amdgcn_sched_barrier(0);

    // 8) 8 x 1KB-contiguous non-temporal stores (full 128B lines/instruction)
    f32x4* ob = (f32x4*)(out + tile * 2048);
#pragma unroll
    for (int s = 0; s < 8; ++s) {
        int p   = lane + 64 * s;      // 16B-chunk index 0..511
        int row = p >> 5;             // 0..15
        int c   = p & 31;
        f32x4 v = *(const f32x4*)(stg + row * 128 + ((c ^ (row & 7)) << 2));
        __builtin_nontemporal_store(v, ob + p);
    }
}

extern "C" void kernel_launch(void* const* d_in, const int* in_sizes, int n_in,
                              void* d_out, int out_size, void* d_ws, size_t ws_size,
                              hipStream_t stream) {
    const float* x      = (const float*)d_in[0];   // [262144,128] fp32
    const float* weight = (const float*)d_in[1];   // [32,32,4] fp32
    const float* bias   = (const float*)d_in[2];   // [128] fp32
    float*       out    = (float*)d_out;           // [262144,128] fp32
    ushort*      wfrag  = (ushort*)d_ws;           // 32 KB fragment-ordered W_eff

    prep_wfrag<<<64, 256, 0, stream>>>(weight, wfrag);
    qgemm<<<4096, 256, 0, stream>>>(x, wfrag, bias, out);
}